// Round 5
// baseline (39.392 us; speedup 1.0000x reference)
//
#include <hip/hip_runtime.h>

#define HH 14
#define WW 14
#define P 196          // HH*WW
#define SENT 196
#define CTOT 2048
#define NCHUNK 16
#define CCHUNK 128     // CTOT/NCHUNK
#define Q4 49          // P/4 float4 per channel row

// d_ws layout: [0, 256) per-batch arrival counters (uint, NEVER initialized --
// the mod-16 election below works from any starting value, 0xAA poison incl.);
// [256, 256 + 1024*196*4) partial sums (written via agent-scope stores).

__global__ __launch_bounds__(256) void fused_kernel(const float* __restrict__ fms,
                                                    unsigned* __restrict__ counters,
                                                    float* __restrict__ partials,
                                                    int* __restrict__ out) {
    const int blk = blockIdx.x;
    const int b = blk >> 4;       // batch
    const int k = blk & 15;       // channel chunk
    const float4* __restrict__ base =
        (const float4*)(fms + ((size_t)b * CTOT + (size_t)k * CCHUNK) * P);

    __shared__ float lds[5 * P];
    __shared__ unsigned oldv;
    const int t = threadIdx.x;

    // ---- phase 1: stream 128 channels, partial-sum per pixel (round-1 code) ----
    if (t < 5 * Q4) {             // 245 active lanes
        const int q = t % Q4;     // float4 column within a channel row
        const int r = t / Q4;     // row-group 0..4
        float4 acc = {0.f, 0.f, 0.f, 0.f};
        #pragma unroll 4
        for (int c = r; c < CCHUNK; c += 5) {
            float4 v = base[c * Q4 + q];
            acc.x += v.x; acc.y += v.y; acc.z += v.z; acc.w += v.w;
        }
        const int o = r * P + q * 4;
        lds[o + 0] = acc.x; lds[o + 1] = acc.y;
        lds[o + 2] = acc.z; lds[o + 3] = acc.w;
    }
    __syncthreads();
    if (t < P) {
        const float s = lds[t] + lds[P + t] + lds[2 * P + t] + lds[3 * P + t] + lds[4 * P + t];
        // write-through to the LLC coherence point; NO fence, NO L2 drain
        __hip_atomic_store(&partials[(size_t)blk * P + t], s,
                           __ATOMIC_RELAXED, __HIP_MEMORY_SCOPE_AGENT);
    }
    asm volatile("s_waitcnt vmcnt(0)" ::: "memory");  // this wave's stores visible
    __syncthreads();                                   // all waves done
    if (t == 0)
        oldv = __hip_atomic_fetch_add(&counters[b], 1u,
                                      __ATOMIC_RELAXED, __HIP_MEMORY_SCOPE_AGENT);
    __syncthreads();
    // exactly one of the 16 consecutive returns is ==15 (mod 16), from ANY start
    if ((oldv & 15u) != 15u) return;

    // ---- phase 2: elected block finishes batch b ----
    __shared__ float att[P];
    __shared__ int lab[P];
    __shared__ int cnt[256];

    if (t < P) {
        float* pb = partials + (size_t)b * NCHUNK * P + t;
        float a = 0.f;
        #pragma unroll
        for (int kk = 0; kk < NCHUNK; ++kk)
            a += __hip_atomic_load(pb + kk * P, __ATOMIC_RELAXED, __HIP_MEMORY_SCOPE_AGENT);
        att[t] = a;
    }
    __syncthreads();
    if (t >= 64) return;          // wave 0 finishes alone (wave-synchronous)

    const int l = t;              // lane 0..63; lanes 0..48 own pixel quads
    float4 a4 = {0.f, 0.f, 0.f, 0.f};
    if (l < Q4) a4 = *(const float4*)(att + 4 * l);
    float mx = (l < Q4) ? fmaxf(fmaxf(a4.x, a4.y), fmaxf(a4.z, a4.w)) : -1e30f;
    #pragma unroll
    for (int off = 32; off >= 1; off >>= 1) mx = fmaxf(mx, __shfl_xor(mx, off));
    const float thr = mx * 0.3f;

    int mymask = 0;
    float av[4] = {a4.x, a4.y, a4.z, a4.w};
    if (l < Q4) {
        #pragma unroll
        for (int j = 0; j < 4; ++j) {
            const int p = 4 * l + j;
            const bool m = av[j] > thr;
            mymask |= (m ? 1 : 0) << j;
            lab[p] = m ? p : SENT;
        }
    }
    asm volatile("s_waitcnt lgkmcnt(0)" ::: "memory");

    // Gauss-Seidel min-label propagation (8-connectivity). Monotone min
    // updates -> order-independent fixed point == reference's Jacobi result.
    for (;;) {
        int changed = 0;
        if (mymask) {
            #pragma unroll
            for (int j = 0; j < 4; ++j) {
                if (mymask & (1 << j)) {
                    const int p = 4 * l + j;
                    const int row = p / WW, col = p % WW;
                    const int cur = lab[p];
                    int m2 = cur;
                    #pragma unroll
                    for (int dr = -1; dr <= 1; ++dr) {
                        const int rr = row + dr;
                        if (rr < 0 || rr >= HH) continue;
                        #pragma unroll
                        for (int dc = -1; dc <= 1; ++dc) {
                            const int cc = col + dc;
                            if (cc < 0 || cc >= WW) continue;
                            m2 = min(m2, lab[rr * WW + cc]);
                        }
                    }
                    if (m2 < cur) { lab[p] = m2; changed = 1; }
                }
            }
        }
        asm volatile("s_waitcnt lgkmcnt(0)" ::: "memory");
        if (!__any(changed)) break;
    }

    // per-label counts
    cnt[l] = 0; cnt[l + 64] = 0; cnt[l + 128] = 0; cnt[l + 192] = 0;
    asm volatile("s_waitcnt lgkmcnt(0)" ::: "memory");
    if (l < Q4) {
        #pragma unroll
        for (int j = 0; j < 4; ++j)
            if (mymask & (1 << j)) atomicAdd(&cnt[lab[4 * l + j]], 1);
    }
    asm volatile("s_waitcnt lgkmcnt(0)" ::: "memory");

    // argmax(count), ties -> smallest label: key = cnt*256 + (255 - label)
    int key = 0;
    if (l < Q4) {
        #pragma unroll
        for (int j = 0; j < 4; ++j) {
            const int p = 4 * l + j;
            key = max(key, cnt[p] * 256 + (255 - p));
        }
    }
    #pragma unroll
    for (int off = 32; off >= 1; off >>= 1) key = max(key, __shfl_xor(key, off));
    const int best = 255 - (key & 255);
    const int bcnt = key >> 8;

    // bbox of selected component (unmasked pixels have lab==SENT != best)
    int mnr = HH, mxr = -1, mnc = WW, mxc = -1;
    if (l < Q4 && bcnt > 0) {
        #pragma unroll
        for (int j = 0; j < 4; ++j) {
            const int p = 4 * l + j;
            if (lab[p] == best) {
                const int row = p / WW, col = p % WW;
                mnr = min(mnr, row); mxr = max(mxr, row);
                mnc = min(mnc, col); mxc = max(mxc, col);
            }
        }
    }
    #pragma unroll
    for (int off = 32; off >= 1; off >>= 1) {
        mnr = min(mnr, __shfl_xor(mnr, off));
        mxr = max(mxr, __shfl_xor(mxr, off));
        mnc = min(mnc, __shfl_xor(mnc, off));
        mxc = max(mxc, __shfl_xor(mxc, off));
    }

    if (l == 0) {
        if (bcnt == 0) { mnr = 0; mxr = HH - 1; mnc = 0; mxc = WW - 1; }  // empty fallback
        out[b * 4 + 0] = max(mnr * 32 - 1, 0);
        out[b * 4 + 1] = max(mnc * 32 - 1, 0);
        out[b * 4 + 2] = (mxr + 1) * 32 - 1;
        out[b * 4 + 3] = (mxc + 1) * 32 - 1;
    }
}

extern "C" void kernel_launch(void* const* d_in, const int* in_sizes, int n_in,
                              void* d_out, int out_size, void* d_ws, size_t ws_size,
                              hipStream_t stream) {
    const float* fms = (const float*)d_in[0];
    int* out = (int*)d_out;
    unsigned* counters = (unsigned*)d_ws;             // 64 uints, no init needed
    float* partials = (float*)((char*)d_ws + 256);    // 1024*196 floats

    fused_kernel<<<dim3(64 * NCHUNK), dim3(256), 0, stream>>>(fms, counters, partials, out);
}

// Round 6
// 31.630 us; speedup vs baseline: 1.2454x; 1.2454x over previous
//
#include <hip/hip_runtime.h>

#define HH 14
#define WW 14
#define P 196          // HH*WW
#define SENT 196
#define CTOT 2048
#define NCHUNK 16
#define CCHUNK 128     // CTOT/NCHUNK
#define Q4 49          // P/4 float4 per channel row

// ---------------- kernel 1: partial channel sums (round-1 exact) ----------------
// grid = 64*NCHUNK = 1024 blocks (fully resident: 4 blocks/CU), 256 threads.
// Block (b,k) sums channels [k*CCHUNK,(k+1)*CCHUNK) into partials[b*16+k][196].
__global__ __launch_bounds__(256) void chansum_kernel(const float* __restrict__ fms,
                                                      float* __restrict__ partials) {
    const int blk = blockIdx.x;
    const int b = blk >> 4;       // /NCHUNK
    const int k = blk & 15;       // %NCHUNK
    const float4* __restrict__ base =
        (const float4*)(fms + ((size_t)b * CTOT + (size_t)k * CCHUNK) * P);

    __shared__ float lds[5 * P];
    const int t = threadIdx.x;

    if (t < 5 * Q4) {             // 245 active lanes
        const int q = t % Q4;     // float4 column within a channel row
        const int r = t / Q4;     // row-group 0..4
        float4 acc = {0.f, 0.f, 0.f, 0.f};
        #pragma unroll 4
        for (int c = r; c < CCHUNK; c += 5) {
            float4 v = base[c * Q4 + q];
            acc.x += v.x; acc.y += v.y; acc.z += v.z; acc.w += v.w;
        }
        const int o = r * P + q * 4;
        lds[o + 0] = acc.x; lds[o + 1] = acc.y;
        lds[o + 2] = acc.z; lds[o + 3] = acc.w;
    }
    __syncthreads();
    if (t < P) {
        float s = lds[t] + lds[P + t] + lds[2 * P + t] + lds[3 * P + t] + lds[4 * P + t];
        partials[(size_t)blk * P + t] = s;
    }
}

// ---------------- kernel 2: threshold + CC + bbox (4-wave parallel) ----------------
// grid = 64 blocks x 256 threads. One pixel per thread. Double-buffered Jacobi
// min-label propagation with __syncthreads_or as fused barrier + convergence
// check (1 barrier/sweep). Labels live in registers after the loop.
__global__ __launch_bounds__(256) void bbox_kernel(const float* __restrict__ partials,
                                                   int* __restrict__ out) {
    const int b = blockIdx.x;
    const int t = threadIdx.x;

    __shared__ int labA[P], labB[P];
    __shared__ int cnt[P];
    __shared__ float redf[4];
    __shared__ int redi[4];
    __shared__ int wr[4][4];

    // attention = sum over 16 partial chunks (coalesced; value kept in register)
    float a = -1e30f;
    if (t < P) {
        const float* pb = partials + (size_t)b * NCHUNK * P + t;
        a = 0.f;
        #pragma unroll
        for (int k = 0; k < NCHUNK; ++k) a += pb[k * P];
    }

    // block max: wave shuffle reduce, then cross-wave combine via LDS
    float mx = a;
    #pragma unroll
    for (int off = 32; off >= 1; off >>= 1) mx = fmaxf(mx, __shfl_xor(mx, off));
    if ((t & 63) == 0) redf[t >> 6] = mx;
    __syncthreads();
    const float maxv = fmaxf(fmaxf(redf[0], redf[1]), fmaxf(redf[2], redf[3]));
    const float thr = maxv * 0.3f;

    const bool maskp = (t < P) && (a > thr);
    const int row = t / WW;
    const int col = t % WW;
    int cur = maskp ? t : SENT;
    if (t < P) labA[t] = cur;
    __syncthreads();

    // double-buffered Jacobi: same monotone fixed point as the reference's
    // 196 fixed iterations; converges in (component diameter + 1) sweeps.
    int pp = 0;
    for (;;) {
        const int* __restrict__ src = pp ? labB : labA;
        int* __restrict__ dst = pp ? labA : labB;
        int m2 = SENT;
        if (maskp) {
            m2 = cur;
            #pragma unroll
            for (int dr = -1; dr <= 1; ++dr) {
                const int rr = row + dr;
                if (rr < 0 || rr >= HH) continue;
                #pragma unroll
                for (int dc = -1; dc <= 1; ++dc) {
                    const int cc = col + dc;
                    if (cc < 0 || cc >= WW) continue;
                    m2 = min(m2, src[rr * WW + cc]);
                }
            }
        }
        if (t < P) dst[t] = m2;
        const int changed = (m2 != cur);
        cur = m2;
        pp ^= 1;
        if (!__syncthreads_or(changed)) break;   // fused barrier + convergence
    }

    // per-label counts (cur holds each thread's final label)
    if (t < P) cnt[t] = 0;
    __syncthreads();
    if (maskp) atomicAdd(&cnt[cur], 1);
    __syncthreads();

    // argmax(count), ties -> smallest label: key = cnt*256 + (255 - label)
    int key = (t < P) ? (cnt[t] * 256 + (255 - t)) : 0;
    #pragma unroll
    for (int off = 32; off >= 1; off >>= 1) key = max(key, __shfl_xor(key, off));
    if ((t & 63) == 0) redi[t >> 6] = key;
    __syncthreads();
    const int bkey = max(max(redi[0], redi[1]), max(redi[2], redi[3]));
    const int best = 255 - (bkey & 255);
    const int bcnt = bkey >> 8;

    // bbox of selected component
    int mnr = HH, mxr = -1, mnc = WW, mxc = -1;
    if (maskp && bcnt > 0 && cur == best) { mnr = row; mxr = row; mnc = col; mxc = col; }
    #pragma unroll
    for (int off = 32; off >= 1; off >>= 1) {
        mnr = min(mnr, __shfl_xor(mnr, off));
        mxr = max(mxr, __shfl_xor(mxr, off));
        mnc = min(mnc, __shfl_xor(mnc, off));
        mxc = max(mxc, __shfl_xor(mxc, off));
    }
    const int wid = t >> 6;
    if ((t & 63) == 0) { wr[0][wid] = mnr; wr[1][wid] = mxr; wr[2][wid] = mnc; wr[3][wid] = mxc; }
    __syncthreads();

    if (t == 0) {
        #pragma unroll
        for (int w = 1; w < 4; ++w) {
            mnr = min(mnr, wr[0][w]); mxr = max(mxr, wr[1][w]);
            mnc = min(mnc, wr[2][w]); mxc = max(mxc, wr[3][w]);
        }
        if (bcnt == 0) { mnr = 0; mxr = HH - 1; mnc = 0; mxc = WW - 1; }  // empty fallback
        out[b * 4 + 0] = max(mnr * 32 - 1, 0);
        out[b * 4 + 1] = max(mnc * 32 - 1, 0);
        out[b * 4 + 2] = (mxr + 1) * 32 - 1;
        out[b * 4 + 3] = (mxc + 1) * 32 - 1;
    }
}

extern "C" void kernel_launch(void* const* d_in, const int* in_sizes, int n_in,
                              void* d_out, int out_size, void* d_ws, size_t ws_size,
                              hipStream_t stream) {
    const float* fms = (const float*)d_in[0];
    int* out = (int*)d_out;
    float* partials = (float*)d_ws;   // 64*NCHUNK*196 floats = 802,816 B

    chansum_kernel<<<dim3(64 * NCHUNK), dim3(256), 0, stream>>>(fms, partials);
    bbox_kernel<<<dim3(64), dim3(256), 0, stream>>>(partials, out);
}